// Round 1
// baseline (9927.734 us; speedup 1.0000x reference)
//
#include <hip/hip_runtime.h>
#include <cstddef>
#include <cstdint>

#define TSTEPS 128
#define BATCH  8192
#define BB     32

typedef _Float16 half8 __attribute__((ext_vector_type(8)));
typedef float    floatx4 __attribute__((ext_vector_type(4)));

// ws layout (bytes)
#define HPRE_OFF   0u            // 8192*256 f32 = 8388608
#define SUM_OFF    8388608u      // 512 f32 (sum[256], sumsq[256])
#define PACK_OFF   8390656u      // packed f16 weights
#define W1P_HALFS  163840        // 5*16*4*512
#define W2P_HALFS  327680        // 5*16*8*512
#define W3P_HALFS  81920         // 5*4*8*512
#define WO1P_HALFS 81920         // 16*10*512
#define WS_NEEDED  (PACK_OFF + (size_t)(W1P_HALFS+W2P_HALFS+W3P_HALFS+WO1P_HALFS)*2)

#define SW(row) (((row)&7)*8)    // LDS xor-swizzle of k/col bits 3..5

// ---------------- pack: f32 weights -> f16 MFMA B-fragment order ----------------
// B-frag for 16x16x32: lane holds W[k = kk*32 + (lane>>4)*8 + j][col = nt*16 + (lane&15)]
__global__ __launch_bounds__(256) void pack_kernel(
    const float* __restrict__ W1, const float* __restrict__ W2,
    const float* __restrict__ W3, const float* __restrict__ Wo1,
    _Float16* __restrict__ w1p, _Float16* __restrict__ w2p,
    _Float16* __restrict__ w3p, _Float16* __restrict__ wo1p,
    float* __restrict__ sums)
{
    int id = blockIdx.x * 256 + threadIdx.x;
    if (id < 512) sums[id] = 0.f;           // zero BN accumulators (ws is poisoned)
    int g = id >> 6;
    int lane = id & 63;
    int q = lane >> 4, cl = lane & 15;
    if (g < 320) {                           // W1 (state part, rows 2..129): g=(n*16+nt)*4+kk
        int kk = g & 3, nt = (g >> 2) & 15, n = g >> 6;
        int col = nt*16 + cl;
        #pragma unroll
        for (int j = 0; j < 8; j++) {
            int r = 2 + kk*32 + q*8 + j;
            w1p[(size_t)id*8 + j] = (_Float16)W1[(n*130 + r)*256 + col];
        }
    } else if (g < 960) {                    // W2: g2=(n*16+nt)*8+kk
        int g2 = g - 320;
        int kk = g2 & 7, nt = (g2 >> 3) & 15, n = g2 >> 7;
        int col = nt*16 + cl;
        #pragma unroll
        for (int j = 0; j < 8; j++) {
            int r = kk*32 + q*8 + j;
            w2p[(size_t)g2*512 + lane*8 + j] = (_Float16)W2[(n*256 + r)*256 + col];
        }
    } else if (g < 1120) {                   // W3: g3=(n*4+nt)*8+kk
        int g3 = g - 960;
        int kk = g3 & 7, nt = (g3 >> 3) & 3, n = g3 >> 5;
        int col = nt*16 + cl;
        #pragma unroll
        for (int j = 0; j < 8; j++) {
            int r = kk*32 + q*8 + j;
            w3p[(size_t)g3*512 + lane*8 + j] = (_Float16)W3[(n*256 + r)*64 + col];
        }
    } else {                                 // Wo1 (state part, rows 5..324): g4=nt*10+kk
        int g4 = g - 1120;
        int kk = g4 % 10, nt = g4 / 10;
        int col = nt*16 + cl;
        #pragma unroll
        for (int j = 0; j < 8; j++) {
            int r = 5 + kk*32 + q*8 + j;
            wo1p[(size_t)g4*512 + lane*8 + j] = (_Float16)Wo1[r*256 + col];
        }
    }
}

// ---------------- the 128-step scan: one block = 32 batch rows ----------------
__global__ __launch_bounds__(512, 2) void scan_kernel(
    const float* __restrict__ x,
    const float* __restrict__ W1, const float* __restrict__ b1,
    const float* __restrict__ b2, const float* __restrict__ b3,
    const float* __restrict__ Wo1, const float* __restrict__ bo1,
    const _Float16* __restrict__ w1p, const _Float16* __restrict__ w2p,
    const _Float16* __restrict__ w3p, const _Float16* __restrict__ wo1p,
    float* __restrict__ hpre)
{
    __shared__ _Float16 Sls[7*32*64];   // 7 state slots (rotating), swizzled
    __shared__ _Float16 H1[32*256];     // layer-1 output (one node), swizzled
    __shared__ _Float16 H2[32*256];     // layer-2 output (one node), swizzled
    __shared__ float    xls[2*5*32];    // x_t double buffer: [buf][node][row]

    const int tid  = threadIdx.x;
    const int w    = tid >> 6;          // wave 0..7
    const int lane = tid & 63;
    const int quad = lane >> 4;
    const int cl   = lane & 15;
    const int b0   = blockIdx.x * BB;

    // zero initial state slots 0..4 (state0 = zeros)
    for (int i = tid; i < 5*32*64; i += 512) Sls[i] = (_Float16)0.f;
    if (tid < 160) {                    // load x_0
        int p = tid >> 5, r = tid & 31;
        xls[p*32 + r] = x[(size_t)(b0 + r)*640 + p*128 + 0];
    }

    // ---- layer 2: H1(32x256,f16) @ W2[n](256x256) -> H2, relu ----
    auto do_L2 = [&](int n) {
        #pragma unroll
        for (int i = 0; i < 2; i++) {
            const int nt = 2*w + i;
            const _Float16* bp = w2p + ((size_t)((n*16 + nt)*8)*64 + lane)*8;
            half8 bf[8];
            #pragma unroll
            for (int kk = 0; kk < 8; kk++) bf[kk] = *(const half8*)(bp + kk*512);
            floatx4 acc0 = {0.f,0.f,0.f,0.f}, acc1 = {0.f,0.f,0.f,0.f};
            #pragma unroll
            for (int kk = 0; kk < 8; kk++) {
                int kb = (kk*32 + quad*8) ^ SW(cl);
                half8 a0 = *(const half8*)&H1[cl*256 + kb];
                half8 a1 = *(const half8*)&H1[(16+cl)*256 + kb];
                acc0 = __builtin_amdgcn_mfma_f32_16x16x32_f16(a0, bf[kk], acc0, 0, 0, 0);
                acc1 = __builtin_amdgcn_mfma_f32_16x16x32_f16(a1, bf[kk], acc1, 0, 0, 0);
            }
            const int colg = nt*16 + cl;
            const float bias = b2[n*256 + colg];
            #pragma unroll
            for (int r = 0; r < 4; r++) {
                int row = quad*4 + r;
                float v0 = acc0[r] + bias; v0 = v0 > 0.f ? v0 : 0.f;
                float v1 = acc1[r] + bias; v1 = v1 > 0.f ? v1 : 0.f;
                int cs = colg ^ SW(row);
                H2[row*256 + cs]      = (_Float16)v0;
                H2[(row+16)*256 + cs] = (_Float16)v1;
            }
        }
    };

    // ---- layer 3: H2 @ W3[n](256x64) -> tanh -> state slot ----
    auto do_L3 = [&](int n, int slot) {
        const int mt = w & 1, nt = w >> 1;   // 8 waves = 2mt x 4nt tiles
        const _Float16* bp = w3p + ((size_t)((n*4 + nt)*8)*64 + lane)*8;
        half8 bf[8];
        #pragma unroll
        for (int kk = 0; kk < 8; kk++) bf[kk] = *(const half8*)(bp + kk*512);
        floatx4 acc = {0.f,0.f,0.f,0.f};
        const int arow = mt*16 + cl;
        #pragma unroll
        for (int kk = 0; kk < 8; kk++) {
            int kb = (kk*32 + quad*8) ^ SW(cl);
            half8 a = *(const half8*)&H2[arow*256 + kb];
            acc = __builtin_amdgcn_mfma_f32_16x16x32_f16(a, bf[kk], acc, 0, 0, 0);
        }
        const int colg = nt*16 + cl;
        const float bias = b3[n*64 + colg];
        #pragma unroll
        for (int r = 0; r < 4; r++) {
            int row = mt*16 + quad*4 + r;
            float v = tanhf(acc[r] + bias);
            Sls[slot*2048 + row*64 + (colg ^ SW(row))] = (_Float16)v;
        }
    };

    // ---- layer 1 for node m: MFMA over parent states (K=128) + VALU rank-2 xg update ----
    auto do_L1 = [&](int m, int sp0, int sp1, int pp0, int pp1, int xb) {
        #pragma unroll
        for (int i = 0; i < 2; i++) {
            const int nt = 2*w + i;
            const _Float16* bp = w1p + ((size_t)((m*16 + nt)*4)*64 + lane)*8;
            half8 bf[4];
            #pragma unroll
            for (int kk = 0; kk < 4; kk++) bf[kk] = *(const half8*)(bp + kk*512);
            floatx4 acc0 = {0.f,0.f,0.f,0.f}, acc1 = {0.f,0.f,0.f,0.f};
            #pragma unroll
            for (int kk = 0; kk < 4; kk++) {
                int slot = (kk < 2) ? sp0 : sp1;
                int fb = ((kk & 1)*32 + quad*8) ^ SW(cl);
                half8 a0 = *(const half8*)&Sls[slot*2048 + cl*64 + fb];
                half8 a1 = *(const half8*)&Sls[slot*2048 + (16+cl)*64 + fb];
                acc0 = __builtin_amdgcn_mfma_f32_16x16x32_f16(a0, bf[kk], acc0, 0, 0, 0);
                acc1 = __builtin_amdgcn_mfma_f32_16x16x32_f16(a1, bf[kk], acc1, 0, 0, 0);
            }
            const int colg = nt*16 + cl;
            const float wx0  = W1[(m*130 + 0)*256 + colg];
            const float wx1  = W1[(m*130 + 1)*256 + colg];
            const float bias = b1[m*256 + colg];
            #pragma unroll
            for (int r = 0; r < 4; r++) {
                int row = quad*4 + r;
                float xa0 = xls[xb*160 + pp0*32 + row];
                float xb0 = xls[xb*160 + pp1*32 + row];
                float xa1 = xls[xb*160 + pp0*32 + row + 16];
                float xb1 = xls[xb*160 + pp1*32 + row + 16];
                float v0 = acc0[r] + bias + xa0*wx0 + xb0*wx1;
                float v1 = acc1[r] + bias + xa1*wx0 + xb1*wx1;
                v0 = v0 > 0.f ? v0 : 0.f;
                v1 = v1 > 0.f ? v1 : 0.f;
                int cs = colg ^ SW(row);
                H1[row*256 + cs]      = (_Float16)v0;
                H1[(row+16)*256 + cs] = (_Float16)v1;
            }
        }
    };

    __syncthreads();

    // 7-slot rotating state allocation; processing order 4,2,0,3,1 (node's parents = {n-2,n-1})
    int l0=0,l1=1,l2=2,l3=3,l4=4,f0=5,f1=6;

    // prologue: L1(4) for t=0 (parents 2,3 at slots l2,l3; x buffer 0)
    do_L1(4, l2, l3, 2, 3, 0);
    __syncthreads();

    for (int t = 0; t < TSTEPS; t++) {
        const int xb = t & 1;
        if (t < TSTEPS-1 && tid < 160) {   // stage x_{t+1}
            int p = tid >> 5, r = tid & 31;
            xls[(xb^1)*160 + p*32 + r] = x[(size_t)(b0 + r)*640 + p*128 + (t+1)];
        }
        do_L2(4);                                     __syncthreads();
        do_L3(4, f0); do_L1(2, l0, l1, 0, 1, xb);     __syncthreads();
        do_L2(2);                                     __syncthreads();
        do_L3(2, f1); do_L1(0, l3, l4, 3, 4, xb);     __syncthreads();
        do_L2(0);                                     __syncthreads();
        do_L3(0, l3); do_L1(3, l1, l2, 1, 2, xb);     __syncthreads();
        do_L2(3);                                     __syncthreads();
        do_L3(3, l1); do_L1(1, l0, l4, 0, 4, xb);     __syncthreads();
        do_L2(1);                                     __syncthreads();
        do_L3(1, l0);
        if (t < TSTEPS-1) do_L1(4, f1, l1, 2, 3, xb^1);  // next step's first L1 (new s2@f1, new s3@l1)
        __syncthreads();
        // rotate: newloc = [l3, l0, f1, l1, f0]; newfree = {l2, l4}
        int a0=l3, a1=l0, a2=f1, a3=l1, a4=f0, nf0=l2, nf1=l4;
        l0=a0; l1=a1; l2=a2; l3=a3; l4=a4; f0=nf0; f1=nf1;
    }

    // ---- head: h_pre = relu(feat @ Wo1 + bo1); feat = [x_127(5), states(320)] ----
    #pragma unroll
    for (int i = 0; i < 2; i++) {
        const int nt = 2*w + i;
        const _Float16* bp = wo1p + ((size_t)(nt*10)*64 + lane)*8;
        half8 bf[10];
        #pragma unroll
        for (int kk = 0; kk < 10; kk++) bf[kk] = *(const half8*)(bp + kk*512);
        floatx4 acc0 = {0.f,0.f,0.f,0.f}, acc1 = {0.f,0.f,0.f,0.f};
        #pragma unroll
        for (int kk = 0; kk < 10; kk++) {
            int nn = kk >> 1;
            int slot = (nn==0)?l0 : (nn==1)?l1 : (nn==2)?l2 : (nn==3)?l3 : l4;
            int fb = ((kk & 1)*32 + quad*8) ^ SW(cl);
            half8 a0 = *(const half8*)&Sls[slot*2048 + cl*64 + fb];
            half8 a1 = *(const half8*)&Sls[slot*2048 + (16+cl)*64 + fb];
            acc0 = __builtin_amdgcn_mfma_f32_16x16x32_f16(a0, bf[kk], acc0, 0, 0, 0);
            acc1 = __builtin_amdgcn_mfma_f32_16x16x32_f16(a1, bf[kk], acc1, 0, 0, 0);
        }
        const int colg = nt*16 + cl;
        const float bias = bo1[colg];
        float wx[5];
        #pragma unroll
        for (int p = 0; p < 5; p++) wx[p] = Wo1[p*256 + colg];
        #pragma unroll
        for (int r = 0; r < 4; r++) {
            int row = quad*4 + r;
            float v0 = acc0[r] + bias, v1 = acc1[r] + bias;
            #pragma unroll
            for (int p = 0; p < 5; p++) {   // x_127 lives in buffer 1 (loaded at t=126)
                v0 += xls[160 + p*32 + row]      * wx[p];
                v1 += xls[160 + p*32 + row + 16] * wx[p];
            }
            v0 = v0 > 0.f ? v0 : 0.f;
            v1 = v1 > 0.f ? v1 : 0.f;
            hpre[(size_t)(b0 + row)*256 + colg]      = v0;
            hpre[(size_t)(b0 + row + 16)*256 + colg] = v1;
        }
    }
}

// ---------------- BN stats: partial sums over batch ----------------
__global__ __launch_bounds__(256) void bnstats_kernel(const float* __restrict__ hpre,
                                                      float* __restrict__ sums)
{
    int col = threadIdx.x;
    int r0 = blockIdx.x * 128;
    float s = 0.f, s2 = 0.f;
    for (int r = 0; r < 128; r++) {
        float v = hpre[(size_t)(r0 + r)*256 + col];
        s += v; s2 += v*v;
    }
    atomicAdd(&sums[col], s);
    atomicAdd(&sums[256 + col], s2);
}

// ---------------- normalize + Wo2 + softmax: one wave per row ----------------
__global__ __launch_bounds__(256) void head_kernel(
    const float* __restrict__ hpre, const float* __restrict__ sums,
    const float* __restrict__ gamma, const float* __restrict__ beta,
    const float* __restrict__ Wo2, const float* __restrict__ bo2,
    float* __restrict__ out)
{
    int row  = blockIdx.x * 4 + (threadIdx.x >> 6);
    int lane = threadIdx.x & 63;
    floatx4 h  = *(const floatx4*)&hpre[(size_t)row*256 + lane*4];
    floatx4 sm = *(const floatx4*)&sums[lane*4];
    floatx4 sq = *(const floatx4*)&sums[256 + lane*4];
    floatx4 g  = *(const floatx4*)&gamma[lane*4];
    floatx4 bb = *(const floatx4*)&beta[lane*4];
    float acc[7] = {0.f,0.f,0.f,0.f,0.f,0.f,0.f};
    #pragma unroll
    for (int e = 0; e < 4; e++) {
        float mu  = sm[e] * (1.f/8192.f);
        float var = sq[e] * (1.f/8192.f) - mu*mu;
        float hn  = (h[e] - mu) * rsqrtf(var + 1e-5f) * g[e] + bb[e];
        int colg = lane*4 + e;
        #pragma unroll
        for (int j = 0; j < 7; j++) acc[j] += hn * Wo2[colg*7 + j];
    }
    #pragma unroll
    for (int off = 1; off < 64; off <<= 1) {
        #pragma unroll
        for (int j = 0; j < 7; j++) acc[j] += __shfl_xor(acc[j], off, 64);
    }
    float z[7], m = -1e30f;
    #pragma unroll
    for (int j = 0; j < 7; j++) { z[j] = acc[j] + bo2[j]; m = fmaxf(m, z[j]); }
    float se = 0.f;
    #pragma unroll
    for (int j = 0; j < 7; j++) { z[j] = expf(z[j] - m); se += z[j]; }
    if (lane < 7) out[(size_t)row*7 + lane] = z[lane] / se;
}

extern "C" void kernel_launch(void* const* d_in, const int* in_sizes, int n_in,
                              void* d_out, int out_size, void* d_ws, size_t ws_size,
                              hipStream_t stream)
{
    const float* x    = (const float*)d_in[0];
    const float* W1   = (const float*)d_in[1];
    const float* b1   = (const float*)d_in[2];
    const float* W2   = (const float*)d_in[3];
    const float* b2   = (const float*)d_in[4];
    const float* W3   = (const float*)d_in[5];
    const float* b3   = (const float*)d_in[6];
    const float* Wo1  = (const float*)d_in[7];
    const float* bo1  = (const float*)d_in[8];
    const float* gamma= (const float*)d_in[9];
    const float* beta = (const float*)d_in[10];
    const float* Wo2  = (const float*)d_in[11];
    const float* bo2  = (const float*)d_in[12];
    float* out = (float*)d_out;

    if (ws_size < WS_NEEDED) return;
    char* ws = (char*)d_ws;
    float*     hpre = (float*)(ws + HPRE_OFF);
    float*     sums = (float*)(ws + SUM_OFF);
    _Float16*  w1p  = (_Float16*)(ws + PACK_OFF);
    _Float16*  w2p  = w1p + W1P_HALFS;
    _Float16*  w3p  = w2p + W2P_HALFS;
    _Float16*  wo1p = w3p + W3P_HALFS;

    pack_kernel<<<320, 256, 0, stream>>>(W1, W2, W3, Wo1, w1p, w2p, w3p, wo1p, sums);
    scan_kernel<<<256, 512, 0, stream>>>(x, W1, b1, b2, b3, Wo1, bo1,
                                         w1p, w2p, w3p, wo1p, hpre);
    bnstats_kernel<<<64, 256, 0, stream>>>(hpre, sums);
    head_kernel<<<2048, 256, 0, stream>>>(hpre, sums, gamma, beta, Wo2, bo2, out);
}